// Round 13
// baseline (89.251 us; speedup 1.0000x reference)
//
#include <hip/hip_runtime.h>
#include <stdint.h>

#define NB 32
#define NM 6300
#define NC 80
#define NTOP 1000
#define NPAD 1024
#define NCAND 2048
#define NBINS 4096

static constexpr float IMGSZ   = 320.0f;
static constexpr float CONF_TH = 0.05f;
static constexpr float NMS_TH  = 0.6f;
static constexpr float EPSF    = 1e-10f;

// ---- workspace layout (bytes, all 16B-aligned) ----
static constexpr size_t OFF_SCORES = 0;                                     // f32 [NB*NM]
static constexpr size_t OFF_LABELS = OFF_SCORES + (size_t)NB * NM * 4;      // i32 [NB*NM]
static constexpr size_t OFF_NBOX   = OFF_LABELS + (size_t)NB * NM * 4;      // f32 [NB*NPAD*4]
static constexpr size_t OFF_NLAB   = OFF_NBOX   + (size_t)NB * NPAD * 16;   // i32 [NB*NPAD]
static constexpr size_t OFF_SUP    = ((OFF_NLAB + (size_t)NB * NPAD * 4) + 1023) & ~(size_t)1023; // u64 [NB*16*16*64]

// ---------------------------------------------------------------------------
// K1: per-anchor score = sigmoid(conf) * max(softmax(cls)), label = argmax.
// PURE streaming kernel — numerics frozen (rank ties depend on them).
// ---------------------------------------------------------------------------
__global__ __launch_bounds__(256) void k_score(const float* __restrict__ conf,
                                               const float* __restrict__ cls,
                                               float* __restrict__ scores,
                                               int* __restrict__ labels) {
#pragma clang fp contract(off)
    int t = blockIdx.x * blockDim.x + threadIdx.x;
    int a = t >> 4;          // anchor index in [0, NB*NM)
    int l = t & 15;
    if (a >= NB * NM) return;
    const float* row = cls + (size_t)a * NC;

    float v[5];
#pragma unroll
    for (int k = 0; k < 5; ++k) v[k] = row[l + 16 * k];

    float bv = v[0];
    int bi = l;
#pragma unroll
    for (int k = 1; k < 5; ++k) {
        int c = l + 16 * k;
        if (v[k] > bv) { bv = v[k]; bi = c; }
    }
#pragma unroll
    for (int m = 1; m < 16; m <<= 1) {
        float ov = __shfl_xor(bv, m, 16);
        int   oi = __shfl_xor(bi, m, 16);
        if (ov > bv || (ov == bv && oi < bi)) { bv = ov; bi = oi; }
    }
    float s = 0.0f;
#pragma unroll
    for (int k = 0; k < 5; ++k) s += expf(v[k] - bv);
#pragma unroll
    for (int m = 1; m < 16; m <<= 1) s += __shfl_xor(s, m, 16);

    if (l == 0) {
        float cf  = conf[a];
        float sig = 1.0f / (1.0f + expf(-cf));
        float inv = 1.0f / s;
        scores[a] = sig * inv;
        labels[a] = bi;
    }
}

// ---------------------------------------------------------------------------
// K2: fused top-k: LDS histogram -> threshold T -> ballot compaction ->
// ALL-PAIRS RANK (broadcast LDS reads, ~5 barriers total, no sort) ->
// fused decode scatter. One block (1024 thr) per batch.
// rank(t) = #{j : key[j] > key[t]}; keys (score_bits<<32 | ~idx) unique
// -> exact lax.top_k order (desc score, ties -> lowest index).
// Each thread ranks its 2 candidates sharing one stream of loaded keys.
// ---------------------------------------------------------------------------
__global__ __launch_bounds__(1024) void k_topk(const float* __restrict__ scores,
                                               const int* __restrict__ labels,
                                               const float* __restrict__ reg,
                                               const float* __restrict__ anchors,
                                               const float* __restrict__ stridemap,
                                               float* __restrict__ out_scores,
                                               float* __restrict__ out_labels,
                                               float* __restrict__ out_boxes,
                                               float* __restrict__ nbox,
                                               int* __restrict__ nlab) {
#pragma clang fp contract(off)
    __shared__ uint32_t hist[NBINS];              // 16 KiB
    __shared__ __align__(16) uint64_t key[NCAND]; // 16 KiB
    __shared__ int sT, scnt;
    int b = blockIdx.x, tid = threadIdx.x;
    const float* sb = scores + (size_t)b * NM;

    for (int i = tid; i < NBINS; i += 1024) hist[i] = 0;
    key[tid] = 0; key[tid + 1024] = 0;            // zero-pad for rank
    if (tid == 0) scnt = 0;
    __syncthreads();

    // LDS histogram of top-12 float bits (scores > 0 -> bit-monotone)
    for (int i = tid; i < NM; i += 1024)
        atomicAdd(&hist[__float_as_uint(sb[i]) >> 20], 1u);
    __syncthreads();

    // threshold bin T (wave 0): 2-stage suffix scan, rotated conflict-free read
    if (tid < 64) {
        int l = tid;
        uint32_t q = 0;
        for (int k = 0; k < 64; ++k) q += hist[l * 64 + ((k + l) & 63)];
        uint32_t s = q;
        for (int off = 1; off < 64; off <<= 1) {
            uint32_t o = __shfl_down(s, off);
            if (l + off < 64) s += o;
        }
        uint64_t m = __ballot(s >= (uint32_t)NTOP);
        int c = 63 - __clzll(m);
        uint32_t sc_ = __shfl(s, c);
        uint32_t qc  = __shfl(q, c);
        uint32_t tail = sc_ - qc;
        uint32_t v = hist[c * 64 + l];
        uint32_t s2 = v;
        for (int off = 1; off < 64; off <<= 1) {
            uint32_t o = __shfl_down(s2, off);
            if (l + off < 64) s2 += o;
        }
        uint64_t m2 = __ballot(s2 + tail >= (uint32_t)NTOP);
        int T = c * 64 + (63 - __clzll(m2));
        if (l == 0) sT = T;
    }
    __syncthreads();

    // ballot compaction of candidates (cross-wave order irrelevant: rank is
    // set-based, keys unique -> outputs bit-identical)
    uint32_t T = (uint32_t)sT;
    int lane = tid & 63;
    for (int i = tid; i < NM; i += 1024) {
        uint32_t bits = __float_as_uint(sb[i]);
        bool pred = (bits >> 20) >= T;
        uint64_t mask = __ballot(pred);
        if (pred) {
            int leader = __ffsll((unsigned long long)mask) - 1;
            int prefix = __popcll(mask & ((1ull << lane) - 1));
            int base = 0;
            if (lane == leader) base = atomicAdd(&scnt, (int)__popcll(mask));
            base = __shfl(base, leader);
            int pos = base + prefix;
            if (pos < NCAND)
                key[pos] = ((uint64_t)bits << 32) | (uint32_t)(~(uint32_t)i);
        }
    }
    __syncthreads();

    // all-pairs rank: thread ranks candidates tid and tid+1024 in one pass.
    // Broadcast LDS reads (uniform j across lanes), 8 words in flight.
    // Pads (0) rank >= C >= NTOP -> auto-gated; no guards needed.
    int C = scnt; if (C > NCAND) C = NCAND;
    int Cr = (C + 15) & ~15;
    uint64_t kt0 = key[tid];
    uint64_t kt1 = key[tid + 1024];
    uint32_t r0 = 0, r1 = 0;
    for (int j = 0; j < Cr; j += 16) {
        const ulonglong2* k2 = (const ulonglong2*)(key + j);
        ulonglong2 a0 = k2[0], a1 = k2[1], a2 = k2[2], a3 = k2[3];
        ulonglong2 a4 = k2[4], a5 = k2[5], a6 = k2[6], a7 = k2[7];
        r0 += (a0.x > kt0) + (a0.y > kt0) + (a1.x > kt0) + (a1.y > kt0);
        r0 += (a2.x > kt0) + (a2.y > kt0) + (a3.x > kt0) + (a3.y > kt0);
        r0 += (a4.x > kt0) + (a4.y > kt0) + (a5.x > kt0) + (a5.y > kt0);
        r0 += (a6.x > kt0) + (a6.y > kt0) + (a7.x > kt0) + (a7.y > kt0);
        r1 += (a0.x > kt1) + (a0.y > kt1) + (a1.x > kt1) + (a1.y > kt1);
        r1 += (a2.x > kt1) + (a2.y > kt1) + (a3.x > kt1) + (a3.y > kt1);
        r1 += (a4.x > kt1) + (a4.y > kt1) + (a5.x > kt1) + (a5.y > kt1);
        r1 += (a6.x > kt1) + (a6.y > kt1) + (a7.x > kt1) + (a7.y > kt1);
    }

    // fused decode scatter for both candidates
#pragma unroll
    for (int cpick = 0; cpick < 2; ++cpick) {
        uint64_t kt   = cpick ? kt1 : kt0;
        uint32_t rank = cpick ? r1  : r0;
        if (rank >= (uint32_t)NTOP) continue;
        uint32_t sbits = (uint32_t)(kt >> 32);
        int idx = (int)(~(uint32_t)kt);
        out_scores[b * NTOP + rank] = __uint_as_float(sbits);
        int lab = labels[(size_t)b * NM + idx];
        out_labels[b * NTOP + rank] = (float)lab;

        const float* rg = reg + ((size_t)b * NM + idx) * 4;
        float rx = rg[0], ry = rg[1], rw = rg[2], rh = rg[3];
        const float* an = anchors + (size_t)idx * 4;
        float ax = an[0], ay = an[1], aw = an[2], ah = an[3];
        float st = stridemap[idx];

        float sx = 1.0f / (1.0f + expf(-rx));
        float sy = 1.0f / (1.0f + expf(-ry));
        float cx = ax + sx * st;
        float cy = ay + sy * st;
        float w  = aw * expf(rw);
        float h  = ah * expf(rh);
        float x1 = cx - 0.5f * w, y1 = cy - 0.5f * h;
        float x2 = cx + 0.5f * w, y2 = cy + 0.5f * h;

        float nx1 = fminf(fmaxf(x1 / IMGSZ, 0.0f), 1.0f);
        float ny1 = fminf(fmaxf(y1 / IMGSZ, 0.0f), 1.0f);
        float nx2 = fminf(fmaxf(x2 / IMGSZ, 0.0f), 1.0f);
        float ny2 = fminf(fmaxf(y2 / IMGSZ, 0.0f), 1.0f);

        float4 bx = make_float4(nx1, ny1, nx2, ny2);
        ((float4*)out_boxes)[b * NTOP + rank] = bx;
        ((float4*)nbox)[b * NPAD + rank]      = bx;
        nlab[b * NPAD + rank] = lab;
    }
}

// ---------------------------------------------------------------------------
// K3: suppression bit-matrix. 256-thr block per 64x64 tile; 4 waves, each
// wave owns 16 columns. lane = row i (box in regs); column box broadcast
// via __shfl (wave-uniform index); column word = __ballot(pred).
// Pad slots [NTOP,NPAD) hold garbage; pred gates them out (iv/jg<NTOP).
// ---------------------------------------------------------------------------
__global__ __launch_bounds__(256) void k_supmat(const float* __restrict__ nbox,
                                                const int* __restrict__ nlab,
                                                uint64_t* __restrict__ sup) {
#pragma clang fp contract(off)
    int b = blockIdx.y;
    int t = blockIdx.x;                 // 0..135 triangular pair index
    int tj = (int)((sqrtf(8.0f * (float)t + 1.0f) - 1.0f) * 0.5f);
    while ((tj + 1) * (tj + 2) / 2 <= t) ++tj;
    while (tj * (tj + 1) / 2 > t) --tj;
    int ti = t - tj * (tj + 1) / 2;

    int lane = threadIdx.x & 63;
    int w    = threadIdx.x >> 6;        // column quarter 0..3

    int i = ti * 64 + lane;             // row owned by this lane
    int j = tj * 64 + lane;             // column data this lane republishes

    float4 bi = ((const float4*)nbox)[b * NPAD + i];
    float  ai = (bi.z - bi.x) * (bi.w - bi.y);
    int    li = nlab[b * NPAD + i];
    float4 bj = ((const float4*)nbox)[b * NPAD + j];
    int    lj = nlab[b * NPAD + j];
    bool   iv = (i < NTOP);

    uint64_t mybits = 0;
#pragma unroll
    for (int u = 0; u < 16; ++u) {
        int jj = (w << 4) | u;          // wave-uniform column index
        float bjx = __shfl(bj.x, jj);
        float bjy = __shfl(bj.y, jj);
        float bjz = __shfl(bj.z, jj);
        float bjw = __shfl(bj.w, jj);
        int   ljv = __shfl(lj, jj);
        float ajv = (bjz - bjx) * (bjw - bjy);
        int   jg  = tj * 64 + jj;
        float xx1 = fmaxf(bi.x, bjx);
        float yy1 = fmaxf(bi.y, bjy);
        float xx2 = fminf(bi.z, bjz);
        float yy2 = fminf(bi.w, bjw);
        float inter = fmaxf(EPSF, xx2 - xx1) * fmaxf(EPSF, yy2 - yy1);
        float uni   = fmaxf(ai + ajv - inter, EPSF);
        float iou   = inter / uni;
        bool pred = (i < jg) && iv && (jg < NTOP) && (li == ljv) && (iou > NMS_TH);
        uint64_t bal = __ballot(pred);
        if (lane == jj) mybits = bal;
    }
    if ((lane >> 4) == w)
        sup[(((size_t)b * 16 + tj) * 16 + ti) * 64 + lane] = mybits;
}

// ---------------------------------------------------------------------------
// K4: greedy NMS scan, 16 waves per batch (wave w = column-block tj=w).
// Jacobi fixpoint within each 64-block == sequential greedy solution.
// ---------------------------------------------------------------------------
__global__ __launch_bounds__(1024) void k_nms(const float* __restrict__ out_scores,
                                              const uint64_t* __restrict__ sup,
                                              float* __restrict__ out_keep) {
    __shared__ uint64_t Kw[16];
    int b    = blockIdx.x;
    int w    = threadIdx.x >> 6;    // wave id = tj block
    int lane = threadIdx.x & 63;
    const uint64_t* supb = sup + (size_t)b * 16 * 16 * 64;

    uint64_t wrow[16];
#pragma unroll
    for (int ti = 0; ti < 16; ++ti)
        wrow[ti] = (ti <= w) ? supb[((size_t)w * 16 + ti) * 64 + lane] : 0ULL;

    int pos = w * 64 + lane;
    bool k0 = (pos < NTOP) && (out_scores[b * NTOP + pos] >= CONF_TH);

    uint64_t ext = 0;
#pragma unroll
    for (int s = 0; s < 16; ++s) {
        if (w == s) {
            bool cand = k0 && (ext == 0ULL);
            uint64_t wself = wrow[s];
            uint64_t alive = __ballot(cand);
            for (int it = 0; it < 64; ++it) {
                bool dead = (wself & alive) != 0ULL;
                uint64_t na = __ballot(cand && !dead);
                if (na == alive) break;
                alive = na;
            }
            if (lane == 0) Kw[s] = alive;
            if (pos < NTOP)
                out_keep[b * NTOP + pos] = ((alive >> lane) & 1ULL) ? 1.0f : 0.0f;
        }
        __syncthreads();
        if (w > s) ext |= wrow[s] & Kw[s];
    }
}

// ---------------------------------------------------------------------------
extern "C" void kernel_launch(void* const* d_in, const int* in_sizes, int n_in,
                              void* d_out, int out_size, void* d_ws, size_t ws_size,
                              hipStream_t stream) {
    const float* conf = (const float*)d_in[0];
    const float* cls  = (const float*)d_in[1];
    const float* reg  = (const float*)d_in[2];
    const float* anch = (const float*)d_in[3];
    const float* strm = (const float*)d_in[4];

    float* out        = (float*)d_out;
    float* out_scores = out;
    float* out_labels = out + NB * NTOP;
    float* out_boxes  = out + 2 * NB * NTOP;
    float* out_keep   = out + 2 * NB * NTOP + NB * NTOP * 4;

    char* ws = (char*)d_ws;
    float*    scores = (float*)(ws + OFF_SCORES);
    int*      labels = (int*)(ws + OFF_LABELS);
    float*    nbox   = (float*)(ws + OFF_NBOX);
    int*      nlab   = (int*)(ws + OFF_NLAB);
    uint64_t* sup    = (uint64_t*)(ws + OFF_SUP);

    k_score<<<(NB * NM * 16) / 256, 256, 0, stream>>>(conf, cls, scores, labels);
    k_topk<<<NB, 1024, 0, stream>>>(scores, labels, reg, anch, strm,
                                    out_scores, out_labels, out_boxes, nbox, nlab);
    k_supmat<<<dim3(136, NB), 256, 0, stream>>>(nbox, nlab, sup);
    k_nms<<<NB, 1024, 0, stream>>>(out_scores, sup, out_keep);
}

// Round 14
// 77.274 us; speedup vs baseline: 1.1550x; 1.1550x over previous
//
#include <hip/hip_runtime.h>
#include <stdint.h>

#define NB 32
#define NM 6300
#define NC 80
#define NTOP 1000
#define NPAD 1024
#define NCAND 2048
#define NBINS 4096
#define CPB 128          // candidates per rank block
#define NRB 16           // rank blocks per batch (NRB*CPB = NCAND)

static constexpr float IMGSZ   = 320.0f;
static constexpr float CONF_TH = 0.05f;
static constexpr float NMS_TH  = 0.6f;
static constexpr float EPSF    = 1e-10f;

// ---- workspace layout (bytes, all 16B-aligned) ----
static constexpr size_t OFF_SCORES = 0;                                     // f32 [NB*NM]
static constexpr size_t OFF_LABELS = OFF_SCORES + (size_t)NB * NM * 4;      // i32 [NB*NM]
static constexpr size_t OFF_CNT    = OFF_LABELS + (size_t)NB * NM * 4;      // i32 [NB]
static constexpr size_t OFF_CAND   = ((OFF_CNT + (size_t)NB * 4) + 15) & ~(size_t)15; // u64 [NB*NCAND]
static constexpr size_t OFF_NBOX   = OFF_CAND   + (size_t)NB * NCAND * 8;   // f32 [NB*NPAD*4]
static constexpr size_t OFF_NLAB   = OFF_NBOX   + (size_t)NB * NPAD * 16;   // i32 [NB*NPAD]
static constexpr size_t OFF_SUP    = ((OFF_NLAB + (size_t)NB * NPAD * 4) + 1023) & ~(size_t)1023; // u64 [NB*16*16*64]

// ---------------------------------------------------------------------------
// K1: per-anchor score = sigmoid(conf) * max(softmax(cls)), label = argmax.
// PURE streaming kernel — numerics frozen (rank ties depend on them).
// ---------------------------------------------------------------------------
__global__ __launch_bounds__(256) void k_score(const float* __restrict__ conf,
                                               const float* __restrict__ cls,
                                               float* __restrict__ scores,
                                               int* __restrict__ labels) {
#pragma clang fp contract(off)
    int t = blockIdx.x * blockDim.x + threadIdx.x;
    int a = t >> 4;          // anchor index in [0, NB*NM)
    int l = t & 15;
    if (a >= NB * NM) return;
    const float* row = cls + (size_t)a * NC;

    float v[5];
#pragma unroll
    for (int k = 0; k < 5; ++k) v[k] = row[l + 16 * k];

    float bv = v[0];
    int bi = l;
#pragma unroll
    for (int k = 1; k < 5; ++k) {
        int c = l + 16 * k;
        if (v[k] > bv) { bv = v[k]; bi = c; }
    }
#pragma unroll
    for (int m = 1; m < 16; m <<= 1) {
        float ov = __shfl_xor(bv, m, 16);
        int   oi = __shfl_xor(bi, m, 16);
        if (ov > bv || (ov == bv && oi < bi)) { bv = ov; bi = oi; }
    }
    float s = 0.0f;
#pragma unroll
    for (int k = 0; k < 5; ++k) s += expf(v[k] - bv);
#pragma unroll
    for (int m = 1; m < 16; m <<= 1) s += __shfl_xor(s, m, 16);

    if (l == 0) {
        float cf  = conf[a];
        float sig = 1.0f / (1.0f + expf(-cf));
        float inv = 1.0f / s;
        scores[a] = sig * inv;
        labels[a] = bi;
    }
}

// ---------------------------------------------------------------------------
// K2a: histogram -> threshold T -> ballot compaction into GLOBAL cand list.
// One block (1024 thr) per batch. The O(C^2) rank is NOT here — it moves to
// k_rank where it can use the whole chip.
// ---------------------------------------------------------------------------
__global__ __launch_bounds__(1024) void k_topkA(const float* __restrict__ scores,
                                                uint64_t* __restrict__ cand,
                                                int* __restrict__ cnt) {
    __shared__ uint32_t hist[NBINS];    // 16 KiB
    __shared__ int sT, scnt;
    int b = blockIdx.x, tid = threadIdx.x;
    const float* sb = scores + (size_t)b * NM;

    for (int i = tid; i < NBINS; i += 1024) hist[i] = 0;
    if (tid == 0) scnt = 0;
    __syncthreads();

    // LDS histogram of top-12 float bits (scores > 0 -> bit-monotone)
    for (int i = tid; i < NM; i += 1024)
        atomicAdd(&hist[__float_as_uint(sb[i]) >> 20], 1u);
    __syncthreads();

    // threshold bin T (wave 0): 2-stage suffix scan, rotated conflict-free read
    if (tid < 64) {
        int l = tid;
        uint32_t q = 0;
        for (int k = 0; k < 64; ++k) q += hist[l * 64 + ((k + l) & 63)];
        uint32_t s = q;
        for (int off = 1; off < 64; off <<= 1) {
            uint32_t o = __shfl_down(s, off);
            if (l + off < 64) s += o;
        }
        uint64_t m = __ballot(s >= (uint32_t)NTOP);
        int c = 63 - __clzll(m);
        uint32_t sc_ = __shfl(s, c);
        uint32_t qc  = __shfl(q, c);
        uint32_t tail = sc_ - qc;
        uint32_t v = hist[c * 64 + l];
        uint32_t s2 = v;
        for (int off = 1; off < 64; off <<= 1) {
            uint32_t o = __shfl_down(s2, off);
            if (l + off < 64) s2 += o;
        }
        uint64_t m2 = __ballot(s2 + tail >= (uint32_t)NTOP);
        int T = c * 64 + (63 - __clzll(m2));
        if (l == 0) sT = T;
    }
    __syncthreads();

    // ballot compaction into global cand (cross-wave order irrelevant: rank
    // is set-based, keys unique -> outputs bit-identical)
    uint32_t T = (uint32_t)sT;
    int lane = tid & 63;
    for (int i = tid; i < NM; i += 1024) {
        uint32_t bits = __float_as_uint(sb[i]);
        bool pred = (bits >> 20) >= T;
        uint64_t mask = __ballot(pred);
        if (pred) {
            int leader = __ffsll((unsigned long long)mask) - 1;
            int prefix = __popcll(mask & ((1ull << lane) - 1));
            int base = 0;
            if (lane == leader) base = atomicAdd(&scnt, (int)__popcll(mask));
            base = __shfl(base, leader);
            int pos = base + prefix;
            if (pos < NCAND)
                cand[(size_t)b * NCAND + pos] =
                    ((uint64_t)bits << 32) | (uint32_t)(~(uint32_t)i);
        }
    }
    __syncthreads();
    if (tid == 0) cnt[b] = (scnt > NCAND) ? NCAND : scnt;
}

// ---------------------------------------------------------------------------
// K2b: all-pairs rank + fused decode, spread over the WHOLE CHIP.
// Grid (NRB=16, NB) x 64 threads: single-wave blocks, 128 candidates each
// (2/thread) -> j-stream LDS reads amortized, ~2 blocks/CU chip-wide.
// rank(t) = #{j : key[j] > key[t]}; keys unique -> exact lax.top_k order.
// Blocks whose slice is beyond C exit immediately (~8 active/batch).
// ---------------------------------------------------------------------------
__global__ __launch_bounds__(64) void k_rank(const uint64_t* __restrict__ cand,
                                             const int* __restrict__ cnt,
                                             const int* __restrict__ labels,
                                             const float* __restrict__ reg,
                                             const float* __restrict__ anchors,
                                             const float* __restrict__ stridemap,
                                             float* __restrict__ out_scores,
                                             float* __restrict__ out_labels,
                                             float* __restrict__ out_boxes,
                                             float* __restrict__ nbox,
                                             int* __restrict__ nlab) {
#pragma clang fp contract(off)
    __shared__ __align__(16) uint64_t key[NCAND];   // 16 KiB
    int b    = blockIdx.y;
    int bx   = blockIdx.x;
    int lane = threadIdx.x;
    int C = cnt[b];
    if (bx * CPB >= C) return;                      // slice empty
    int Cr = (C + 15) & ~15;

    const uint64_t* cb = cand + (size_t)b * NCAND;
    for (int i = lane; i < Cr; i += 64)
        key[i] = (i < C) ? cb[i] : 0ULL;
    __syncthreads();

    int c0 = bx * CPB + lane;           // candidate 0
    int c1 = c0 + 64;                   // candidate 1
    uint64_t kt0 = (c0 < Cr) ? key[c0] : 0ULL;
    uint64_t kt1 = (c1 < Cr) ? key[c1] : 0ULL;

    uint32_t r0 = 0, r1 = 0;
    for (int j = 0; j < Cr; j += 16) {
        const ulonglong2* k2 = (const ulonglong2*)(key + j);
        ulonglong2 a0 = k2[0], a1 = k2[1], a2 = k2[2], a3 = k2[3];
        ulonglong2 a4 = k2[4], a5 = k2[5], a6 = k2[6], a7 = k2[7];
        r0 += (a0.x > kt0) + (a0.y > kt0) + (a1.x > kt0) + (a1.y > kt0);
        r0 += (a2.x > kt0) + (a2.y > kt0) + (a3.x > kt0) + (a3.y > kt0);
        r0 += (a4.x > kt0) + (a4.y > kt0) + (a5.x > kt0) + (a5.y > kt0);
        r0 += (a6.x > kt0) + (a6.y > kt0) + (a7.x > kt0) + (a7.y > kt0);
        r1 += (a0.x > kt1) + (a0.y > kt1) + (a1.x > kt1) + (a1.y > kt1);
        r1 += (a2.x > kt1) + (a2.y > kt1) + (a3.x > kt1) + (a3.y > kt1);
        r1 += (a4.x > kt1) + (a4.y > kt1) + (a5.x > kt1) + (a5.y > kt1);
        r1 += (a6.x > kt1) + (a6.y > kt1) + (a7.x > kt1) + (a7.y > kt1);
    }

#pragma unroll
    for (int cpick = 0; cpick < 2; ++cpick) {
        uint64_t kt   = cpick ? kt1 : kt0;
        uint32_t rank = cpick ? r1  : r0;
        if (rank >= (uint32_t)NTOP) continue;       // pads: rank >= C >= NTOP
        uint32_t sbits = (uint32_t)(kt >> 32);
        int idx = (int)(~(uint32_t)kt);
        out_scores[b * NTOP + rank] = __uint_as_float(sbits);
        int lab = labels[(size_t)b * NM + idx];
        out_labels[b * NTOP + rank] = (float)lab;

        const float* rg = reg + ((size_t)b * NM + idx) * 4;
        float rx = rg[0], ry = rg[1], rw = rg[2], rh = rg[3];
        const float* an = anchors + (size_t)idx * 4;
        float ax = an[0], ay = an[1], aw = an[2], ah = an[3];
        float st = stridemap[idx];

        float sx = 1.0f / (1.0f + expf(-rx));
        float sy = 1.0f / (1.0f + expf(-ry));
        float cx = ax + sx * st;
        float cy = ay + sy * st;
        float w  = aw * expf(rw);
        float h  = ah * expf(rh);
        float x1 = cx - 0.5f * w, y1 = cy - 0.5f * h;
        float x2 = cx + 0.5f * w, y2 = cy + 0.5f * h;

        float nx1 = fminf(fmaxf(x1 / IMGSZ, 0.0f), 1.0f);
        float ny1 = fminf(fmaxf(y1 / IMGSZ, 0.0f), 1.0f);
        float nx2 = fminf(fmaxf(x2 / IMGSZ, 0.0f), 1.0f);
        float ny2 = fminf(fmaxf(y2 / IMGSZ, 0.0f), 1.0f);

        float4 bx4 = make_float4(nx1, ny1, nx2, ny2);
        ((float4*)out_boxes)[b * NTOP + rank] = bx4;
        ((float4*)nbox)[b * NPAD + rank]      = bx4;
        nlab[b * NPAD + rank] = lab;
    }
}

// ---------------------------------------------------------------------------
// K3: suppression bit-matrix. 256-thr block per 64x64 tile; 4 waves, each
// wave owns 16 columns. lane = row i (box in regs); column box broadcast
// via __shfl (wave-uniform index); column word = __ballot(pred).
// Pad slots [NTOP,NPAD) hold garbage; pred gates them out (iv/jg<NTOP).
// ---------------------------------------------------------------------------
__global__ __launch_bounds__(256) void k_supmat(const float* __restrict__ nbox,
                                                const int* __restrict__ nlab,
                                                uint64_t* __restrict__ sup) {
#pragma clang fp contract(off)
    int b = blockIdx.y;
    int t = blockIdx.x;                 // 0..135 triangular pair index
    int tj = (int)((sqrtf(8.0f * (float)t + 1.0f) - 1.0f) * 0.5f);
    while ((tj + 1) * (tj + 2) / 2 <= t) ++tj;
    while (tj * (tj + 1) / 2 > t) --tj;
    int ti = t - tj * (tj + 1) / 2;

    int lane = threadIdx.x & 63;
    int w    = threadIdx.x >> 6;        // column quarter 0..3

    int i = ti * 64 + lane;             // row owned by this lane
    int j = tj * 64 + lane;             // column data this lane republishes

    float4 bi = ((const float4*)nbox)[b * NPAD + i];
    float  ai = (bi.z - bi.x) * (bi.w - bi.y);
    int    li = nlab[b * NPAD + i];
    float4 bj = ((const float4*)nbox)[b * NPAD + j];
    int    lj = nlab[b * NPAD + j];
    bool   iv = (i < NTOP);

    uint64_t mybits = 0;
#pragma unroll
    for (int u = 0; u < 16; ++u) {
        int jj = (w << 4) | u;          // wave-uniform column index
        float bjx = __shfl(bj.x, jj);
        float bjy = __shfl(bj.y, jj);
        float bjz = __shfl(bj.z, jj);
        float bjw = __shfl(bj.w, jj);
        int   ljv = __shfl(lj, jj);
        float ajv = (bjz - bjx) * (bjw - bjy);
        int   jg  = tj * 64 + jj;
        float xx1 = fmaxf(bi.x, bjx);
        float yy1 = fmaxf(bi.y, bjy);
        float xx2 = fminf(bi.z, bjz);
        float yy2 = fminf(bi.w, bjw);
        float inter = fmaxf(EPSF, xx2 - xx1) * fmaxf(EPSF, yy2 - yy1);
        float uni   = fmaxf(ai + ajv - inter, EPSF);
        float iou   = inter / uni;
        bool pred = (i < jg) && iv && (jg < NTOP) && (li == ljv) && (iou > NMS_TH);
        uint64_t bal = __ballot(pred);
        if (lane == jj) mybits = bal;
    }
    if ((lane >> 4) == w)
        sup[(((size_t)b * 16 + tj) * 16 + ti) * 64 + lane] = mybits;
}

// ---------------------------------------------------------------------------
// K4: greedy NMS scan, 16 waves per batch (wave w = column-block tj=w).
// Jacobi fixpoint within each 64-block == sequential greedy solution.
// ---------------------------------------------------------------------------
__global__ __launch_bounds__(1024) void k_nms(const float* __restrict__ out_scores,
                                              const uint64_t* __restrict__ sup,
                                              float* __restrict__ out_keep) {
    __shared__ uint64_t Kw[16];
    int b    = blockIdx.x;
    int w    = threadIdx.x >> 6;    // wave id = tj block
    int lane = threadIdx.x & 63;
    const uint64_t* supb = sup + (size_t)b * 16 * 16 * 64;

    uint64_t wrow[16];
#pragma unroll
    for (int ti = 0; ti < 16; ++ti)
        wrow[ti] = (ti <= w) ? supb[((size_t)w * 16 + ti) * 64 + lane] : 0ULL;

    int pos = w * 64 + lane;
    bool k0 = (pos < NTOP) && (out_scores[b * NTOP + pos] >= CONF_TH);

    uint64_t ext = 0;
#pragma unroll
    for (int s = 0; s < 16; ++s) {
        if (w == s) {
            bool cand = k0 && (ext == 0ULL);
            uint64_t wself = wrow[s];
            uint64_t alive = __ballot(cand);
            for (int it = 0; it < 64; ++it) {
                bool dead = (wself & alive) != 0ULL;
                uint64_t na = __ballot(cand && !dead);
                if (na == alive) break;
                alive = na;
            }
            if (lane == 0) Kw[s] = alive;
            if (pos < NTOP)
                out_keep[b * NTOP + pos] = ((alive >> lane) & 1ULL) ? 1.0f : 0.0f;
        }
        __syncthreads();
        if (w > s) ext |= wrow[s] & Kw[s];
    }
}

// ---------------------------------------------------------------------------
extern "C" void kernel_launch(void* const* d_in, const int* in_sizes, int n_in,
                              void* d_out, int out_size, void* d_ws, size_t ws_size,
                              hipStream_t stream) {
    const float* conf = (const float*)d_in[0];
    const float* cls  = (const float*)d_in[1];
    const float* reg  = (const float*)d_in[2];
    const float* anch = (const float*)d_in[3];
    const float* strm = (const float*)d_in[4];

    float* out        = (float*)d_out;
    float* out_scores = out;
    float* out_labels = out + NB * NTOP;
    float* out_boxes  = out + 2 * NB * NTOP;
    float* out_keep   = out + 2 * NB * NTOP + NB * NTOP * 4;

    char* ws = (char*)d_ws;
    float*    scores = (float*)(ws + OFF_SCORES);
    int*      labels = (int*)(ws + OFF_LABELS);
    int*      cnt    = (int*)(ws + OFF_CNT);
    uint64_t* cand   = (uint64_t*)(ws + OFF_CAND);
    float*    nbox   = (float*)(ws + OFF_NBOX);
    int*      nlab   = (int*)(ws + OFF_NLAB);
    uint64_t* sup    = (uint64_t*)(ws + OFF_SUP);

    k_score<<<(NB * NM * 16) / 256, 256, 0, stream>>>(conf, cls, scores, labels);
    k_topkA<<<NB, 1024, 0, stream>>>(scores, cand, cnt);
    k_rank<<<dim3(NRB, NB), 64, 0, stream>>>(cand, cnt, labels, reg, anch, strm,
                                             out_scores, out_labels, out_boxes,
                                             nbox, nlab);
    k_supmat<<<dim3(136, NB), 256, 0, stream>>>(nbox, nlab, sup);
    k_nms<<<NB, 1024, 0, stream>>>(out_scores, sup, out_keep);
}